// Round 10
// baseline (214.967 us; speedup 1.0000x reference)
//
#include <hip/hip_runtime.h>
#include <hip/hip_bf16.h>

// Problem constants (fixed by setup_inputs)
#define NXc 16384
#define DHc 128          // d_hidden
#define DLc 64           // d_latent
#define Kc  3            // neighbor radius
#define Wc  7            // 2k+1 offsets
#define Pc  32           // points per block
#define NTc 256          // threads per block
#define HALO 38          // Pc + 2*Kc
#define RB  272          // bf16 activation LDS row stride (128*2 + 16 pad)

typedef __attribute__((ext_vector_type(8))) short short8;   // 8 bf16 = one MFMA A/B fragment
typedef __attribute__((ext_vector_type(4))) float f32x4;    // MFMA accumulator
typedef __attribute__((ext_vector_type(2))) float f32x2;    // packed fp32 (v_pk_* target)

// LDS layout (bytes) for the main kernel.
#define OFF_U  0                    // 38 fp32 (pad to 160)
#define OFF_X  160                  // -> 320
#define OFF_GN 320                  // bf16 [32][RB] = 8704 -> 9024
#define OFF_S  9024                 // -> 17728
#define OFF_H2 17728                // -> 26432
#define SMEM_BYTES 26432            // 6 blocks/CU

// d_ws layout — TOTAL 82432 bytes (the envelope proven safe through round 7;
// round 9's 224KB staging overran ws_size and corrupted harness buffers):
//   [0, 81920)     : bf16 fragments (M1 16384 el, M2 16384 el, CW2 8192 el)
//   [81920, 82432) : fb, 128 fp32 (fused bias)
#define WS_M1  0
#define WS_M2  16384
#define WS_CW2 32768
#define FB_OFF_BYTES  81920

#if __has_builtin(__builtin_amdgcn_exp2f)
#define EXP2F(x) __builtin_amdgcn_exp2f(x)
#else
#define EXP2F(x) exp2f(x)
#endif
#if __has_builtin(__builtin_amdgcn_rcpf)
#define RCPF(x) __builtin_amdgcn_rcpf(x)
#else
#define RCPF(x) (1.0f / (x))
#endif

// tanh-form GELU via sigmoid: gelu(x) = x / (1 + exp2(x*(c0 + c1*x^2)))
#define GC0 -2.30220838f
#define GC1 -0.10294325f

__device__ __forceinline__ f32x2 vfma(f32x2 a, f32x2 b, f32x2 c) {
    return __builtin_elementwise_fma(a, b, c);
}
__device__ __forceinline__ f32x2 splat2(float s) { f32x2 v = {s, s}; return v; }

// Paired gelu on a packed float2: one rcp for two gelus (exact pairing identity).
__device__ __forceinline__ f32x2 gelu2v(f32x2 xv) {
    xv = __builtin_elementwise_max(xv, splat2(-8.0f));
    f32x2 z = xv * vfma(splat2(GC1), xv * xv, splat2(GC0));
    f32x2 t;
    t.x = EXP2F(z.x);
    t.y = EXP2F(z.y);
    t = t + splat2(1.0f);
    float rr = RCPF(t.x * t.y);
    f32x2 ts = {t.y, t.x};
    return xv * ts * splat2(rr);
}

__device__ __forceinline__ void gelu2_accv(f32x2 xv, f32x2& acc) {
    f32x2 z = xv * vfma(splat2(GC1), xv * xv, splat2(GC0));
    f32x2 t;
    t.x = EXP2F(z.x);
    t.y = EXP2F(z.y);
    t = t + splat2(1.0f);
    float rr = RCPF(t.x * t.y);
    f32x2 ts = {t.y, t.x};
    acc = vfma(xv * ts, splat2(rr), acc);
}

#if __has_builtin(__builtin_amdgcn_cvt_pk_bf16_f32)
typedef __attribute__((ext_vector_type(2))) __bf16 bf16x2_t;
__device__ __forceinline__ unsigned pack_bf16(float a, float b) {
    bf16x2_t v = __builtin_amdgcn_cvt_pk_bf16_f32(a, b);
    unsigned r; __builtin_memcpy(&r, &v, 4); return r;
}
#else
__device__ __forceinline__ unsigned bf16rne(float a) {
    unsigned u;
    __builtin_memcpy(&u, &a, 4);
    return u + 0x7FFFu + ((u >> 16) & 1u);
}
__device__ __forceinline__ unsigned pack_bf16(float a, float b) {
    return (bf16rne(a) >> 16) | (bf16rne(b) & 0xFFFF0000u);
}
#endif
__device__ __forceinline__ void store_bf16x4(void* p, float a, float b, float c, float d) {
    uint2 u;
    u.x = pack_bf16(a, b);
    u.y = pack_bf16(c, d);
    *(uint2*)p = u;
}

// ---- fold+pack in ONE kernel, no global staging (stays inside 82432B ws) ----
// Blocks 0..7: mat = blk>>2 (0:M1=nw2@cw1_top, 1:M2=ew2@cw1_bot), kt = blk&3.
//   Step 1: LDS slab[kl][n] = sum_q head[(kt*32+kl)*64+q] * crows[q*128+n]  (fp32)
//   Step 2: pack 8 fragments (nt=0..7): ws[matbase + (nt*4+kt)*512 + l*8 + j]
//           = bf16(slab[(l>>4)*8+j][nt*16+(l&15)])
// Block 8: cw2 fragment pack (no fold) + fb[n] = cb1[n] + nb2@cw1_top + 7*eb2@cw1_bot.
__global__ void fold_pack(const float* __restrict__ nw2, const float* __restrict__ ew2,
                          const float* __restrict__ cw1, const float* __restrict__ cw2,
                          const float* __restrict__ nb2, const float* __restrict__ eb2,
                          const float* __restrict__ cb1, __hip_bfloat16* __restrict__ ws,
                          float* __restrict__ fb)
{
    __shared__ float slab[32][DHc];
    const int tid = threadIdx.x;
    const int blk = blockIdx.x;

    if (blk < 8) {
        const int mat = blk >> 2, kt = blk & 3;
        const float* head  = mat ? ew2 : nw2;                 // [128][64]
        const float* crows = mat ? (cw1 + 64 * DHc) : cw1;    // 64 rows of cw1
        // Step 1: compute the 32x128 fold slab in fp32
        for (int idx = tid; idx < 32 * DHc; idx += NTc) {
            int kl = idx >> 7, n = idx & 127;
            int k = kt * 32 + kl;
            float acc = 0.f;
            for (int q = 0; q < 64; ++q)
                acc = fmaf(head[k * 64 + q], crows[q * DHc + n], acc);
            slab[kl][n] = acc;
        }
        __syncthreads();
        // Step 2: pack 8 fragments for this kt
        const int matbase = mat ? WS_M2 : WS_M1;
        for (int idx = tid; idx < 8 * 512; idx += NTc) {
            int nt = idx >> 9, r = idx & 511;
            int l = r >> 3, j = r & 7;
            int kl = (l >> 4) * 8 + j;
            int n = nt * 16 + (l & 15);
            ws[matbase + (nt * 4 + kt) * 512 + r] = __float2bfloat16(slab[kl][n]);
        }
    } else {
        // cw2 fragment pack (N=64), verified mapping
        for (int e = tid; e < 8192; e += NTc) {
            int f = e >> 9, l = (e >> 3) & 63, j = e & 7;
            int nt = f >> 2, kt = f & 3;
            int k = kt * 32 + (l >> 4) * 8 + j;
            int n = nt * 16 + (l & 15);
            ws[WS_CW2 + e] = __float2bfloat16(cw2[k * DLc + n]);
        }
        // fused bias
        if (tid < DHc) {
            int n = tid;
            float acc = cb1[n];
            for (int q = 0; q < 64; ++q)
                acc = fmaf(nb2[q], cw1[q * DHc + n], acc);
            for (int q = 0; q < 64; ++q)
                acc = fmaf(7.0f * eb2[q], cw1[(64 + q) * DHc + n], acc);
            fb[n] = acc;
        }
    }
}

__global__ __launch_bounds__(NTc, 6)
void lifting_mfma(const float* __restrict__ u0, const float* __restrict__ x,
                  const float* __restrict__ nw1, const float* __restrict__ nb1,
                  const float* __restrict__ eb1, const float* __restrict__ ew1,
                  const float* __restrict__ cb2,
                  const short8* __restrict__ wsv, const float* __restrict__ fbp,
                  float* __restrict__ out)
{
    __shared__ char sm[SMEM_BYTES];
    float* s_u = (float*)(sm + OFF_U);
    float* s_x = (float*)(sm + OFF_X);

    const int tid   = threadIdx.x;
    const int wave  = tid >> 6;
    const int lane  = tid & 63;
    const int quad  = lane >> 4;
    const int l15   = lane & 15;
    const int tiles = NXc / Pc;
    const int b     = blockIdx.x / tiles;
    const int i0    = (blockIdx.x % tiles) * Pc;
    const float* ub = u0 + (size_t)b * NXc;
    const float* xb = x  + (size_t)b * NXc;

    // ---- Phase 0: halo load with clamp ----
    if (tid < HALO) {
        int i = i0 - Kc + tid;
        i = i < 0 ? 0 : (i >= NXc ? NXc - 1 : i);
        s_u[tid] = ub[i];
        s_x[tid] = xb[i];
    }
    __syncthreads();

    // ---- Phase B (fused, packed-fp32): thread owns dim-quad jq for 4 CONSECUTIVE
    //      points; 10-row c-window in registers as f32x2 pairs. ----
    {
        const int jq = tid & 31;
        const int pbase = (tid >> 5) * 4;
        const int j0 = jq * 4;
        const f32x2 w0l = *(const f32x2*)(nw1 + j0),           w0h = *(const f32x2*)(nw1 + j0 + 2);
        const f32x2 w1l = *(const f32x2*)(nw1 + DHc + j0),     w1h = *(const f32x2*)(nw1 + DHc + j0 + 2);
        const f32x2 nbl = *(const f32x2*)(nb1 + j0),           nbh = *(const f32x2*)(nb1 + j0 + 2);
        const f32x2 e0l = *(const f32x2*)(ew1 + j0),           e0h = *(const f32x2*)(ew1 + j0 + 2);
        const f32x2 e1l = *(const f32x2*)(ew1 + DHc + j0),     e1h = *(const f32x2*)(ew1 + DHc + j0 + 2);
        const f32x2 e2l = *(const f32x2*)(ew1 + 2 * DHc + j0), e2h = *(const f32x2*)(ew1 + 2 * DHc + j0 + 2);
        const f32x2 bel = *(const f32x2*)(eb1 + j0),           beh = *(const f32x2*)(eb1 + j0 + 2);

        float su[10], sx[10];
        #pragma unroll
        for (int r = 0; r < 10; ++r) {
            su[r] = s_u[pbase + r];
            sx[r] = s_x[pbase + r];
        }

        f32x2 cwl[10], cwh[10];
        #pragma unroll
        for (int r = 0; r < 10; ++r) {
            f32x2 uv = splat2(su[r]), xv = splat2(sx[r]);
            cwl[r] = vfma(uv, e1l, xv * e2l);
            cwh[r] = vfma(uv, e1h, xv * e2h);
        }

        #pragma unroll
        for (int r0 = 0; r0 < 4; ++r0) {
            const int p = pbase + r0;
            const f32x2 uv = splat2(su[r0 + 3]), xv = splat2(sx[r0 + 3]);

            f32x2 gl = gelu2v(vfma(uv, w0l, vfma(xv, w1l, nbl)));
            f32x2 gh = gelu2v(vfma(uv, w0h, vfma(xv, w1h, nbh)));
            store_bf16x4(sm + OFF_GN + p * RB + j0 * 2, gl.x, gl.y, gh.x, gh.y);

            f32x2 al = vfma(uv, e0l, bel - xv * e2l);
            f32x2 ah = vfma(uv, e0h, beh - xv * e2h);
            f32x2 accl = {0.f, 0.f}, acch = {0.f, 0.f};
            #pragma unroll
            for (int o = 0; o < Wc; ++o) {
                gelu2_accv(al + cwl[r0 + o], accl);
                gelu2_accv(ah + cwh[r0 + o], acch);
            }
            store_bf16x4(sm + OFF_S + p * RB + j0 * 2, accl.x, accl.y, acch.x, acch.y);
        }
    }
    __syncthreads();

    // ---- Phase C' (MFMA, folded C+D): h2 = gelu(gn@M1 + s@M2 + fb). ----
    {
        const int mt = wave & 1, nh = wave >> 1;
        const int rowbase = mt * 16;
        const short8* M1 = wsv + (WS_M1 >> 3);
        const short8* M2 = wsv + (WS_M2 >> 3);
        f32x4 acc[4] = {{0,0,0,0},{0,0,0,0},{0,0,0,0},{0,0,0,0}};
        #pragma unroll
        for (int kt = 0; kt < 4; ++kt) {
            short8 ag = *(const short8*)(sm + OFF_GN + (rowbase + l15) * RB + kt * 64 + quad * 16);
            short8 as = *(const short8*)(sm + OFF_S  + (rowbase + l15) * RB + kt * 64 + quad * 16);
            #pragma unroll
            for (int t = 0; t < 4; ++t) {
                int nt = nh * 4 + t;
                short8 m1f = M1[(nt * 4 + kt) * 64 + lane];
                short8 m2f = M2[(nt * 4 + kt) * 64 + lane];
                acc[t] = __builtin_amdgcn_mfma_f32_16x16x32_bf16(m1f, ag, acc[t], 0, 0, 0);
                acc[t] = __builtin_amdgcn_mfma_f32_16x16x32_bf16(m2f, as, acc[t], 0, 0, 0);
            }
        }
        const int p = rowbase + l15;
        #pragma unroll
        for (int t = 0; t < 4; ++t) {
            int nbase = (nh * 4 + t) * 16 + quad * 4;
            float4 cb = ((const float4*)fbp)[nbase >> 2];
            f32x2 pl = {acc[t][0] + cb.x, acc[t][1] + cb.y};
            f32x2 ph = {acc[t][2] + cb.z, acc[t][3] + cb.w};
            f32x2 hl = gelu2v(pl), hh = gelu2v(ph);
            store_bf16x4(sm + OFF_H2 + p * RB + nbase * 2, hl.x, hl.y, hh.x, hh.y);
        }
    }
    __syncthreads();

    // ---- Phase E (MFMA): out = h2 @ cw2 + cb2, float4 straight to global ----
    {
        const int mt = wave & 1, nh = wave >> 1;
        const int rowbase = mt * 16;
        const short8* Bmat = wsv + (WS_CW2 >> 3);
        f32x4 acc[2] = {{0,0,0,0},{0,0,0,0}};
        #pragma unroll
        for (int kt = 0; kt < 4; ++kt) {
            short8 af = *(const short8*)(sm + OFF_H2 + (rowbase + l15) * RB + kt * 64 + quad * 16);
            #pragma unroll
            for (int t = 0; t < 2; ++t) {
                int nt = nh * 2 + t;
                short8 wf = Bmat[(nt * 4 + kt) * 64 + lane];
                acc[t] = __builtin_amdgcn_mfma_f32_16x16x32_bf16(wf, af, acc[t], 0, 0, 0);
            }
        }
        const int p = rowbase + l15;
        float* outb = out + ((size_t)b * NXc + i0 + p) * DLc;
        #pragma unroll
        for (int t = 0; t < 2; ++t) {
            int nbase = (nh * 2 + t) * 16 + quad * 4;
            float4 cb = ((const float4*)cb2)[nbase >> 2];
            float4 v;
            v.x = acc[t][0] + cb.x;
            v.y = acc[t][1] + cb.y;
            v.z = acc[t][2] + cb.z;
            v.w = acc[t][3] + cb.w;
            *(float4*)(outb + nbase) = v;
        }
    }
}

extern "C" void kernel_launch(void* const* d_in, const int* in_sizes, int n_in,
                              void* d_out, int out_size, void* d_ws, size_t ws_size,
                              hipStream_t stream) {
    const float* u0  = (const float*)d_in[0];
    const float* x   = (const float*)d_in[1];
    const float* nw1 = (const float*)d_in[2];
    const float* nb1 = (const float*)d_in[3];
    const float* nw2 = (const float*)d_in[4];
    const float* nb2 = (const float*)d_in[5];
    const float* ew1 = (const float*)d_in[6];
    const float* eb1 = (const float*)d_in[7];
    const float* ew2 = (const float*)d_in[8];
    const float* eb2 = (const float*)d_in[9];
    const float* cw1 = (const float*)d_in[10];
    const float* cb1 = (const float*)d_in[11];
    const float* cw2 = (const float*)d_in[12];
    const float* cb2 = (const float*)d_in[13];
    float* out = (float*)d_out;

    __hip_bfloat16* ws = (__hip_bfloat16*)d_ws;
    float* fb = (float*)((char*)d_ws + FB_OFF_BYTES);

    fold_pack<<<9, NTc, 0, stream>>>(nw2, ew2, cw1, cw2, nb2, eb2, cb1, ws, fb);

    const int grid = 16 * (NXc / Pc);   // 8192 blocks
    lifting_mfma<<<grid, NTc, 0, stream>>>(u0, x, nw1, nb1, eb1, ew1, cb2,
                                           (const short8*)d_ws, fb, out);
}